// Round 1
// baseline (188.933 us; speedup 1.0000x reference)
//
#include <hip/hip_runtime.h>
#include <math.h>

// ---- float <-> order-preserving uint key (for global min/max via atomics) ----
static __device__ __forceinline__ unsigned fkey(float f) {
  unsigned u = __float_as_uint(f);
  return (u & 0x80000000u) ? ~u : (u | 0x80000000u);
}
static __device__ __forceinline__ float funkey(unsigned u) {
  unsigned b = (u & 0x80000000u) ? (u & 0x7FFFFFFFu) : ~u;
  return __uint_as_float(b);
}

__global__ __launch_bounds__(64) void init_minmax(unsigned* ws) {
  if (threadIdx.x == 0) { ws[0] = 0xFFFFFFFFu; ws[1] = 0u; }
}

__global__ __launch_bounds__(256) void minmax_kernel(const float4* __restrict__ d,
                                                     unsigned* __restrict__ ws, int n4) {
  int idx = blockIdx.x * 256 + threadIdx.x;
  int stride = gridDim.x * 256;
  float lmin = INFINITY, lmax = -INFINITY;
  for (int i = idx; i < n4; i += stride) {
    float4 v = d[i];
    lmin = fminf(lmin, fminf(fminf(v.x, v.y), fminf(v.z, v.w)));
    lmax = fmaxf(lmax, fmaxf(fmaxf(v.x, v.y), fmaxf(v.z, v.w)));
  }
#pragma unroll
  for (int off = 32; off; off >>= 1) {
    lmin = fminf(lmin, __shfl_xor(lmin, off));
    lmax = fmaxf(lmax, __shfl_xor(lmax, off));
  }
  if ((threadIdx.x & 63) == 0) {
    atomicMin(&ws[0], fkey(lmin));
    atomicMax(&ws[1], fkey(lmax));
  }
}

// One wave (64 lanes) per ray; lane = sample index s in [0,64).
// S=64, C=32 hard-coded per problem shapes.
__global__ __launch_bounds__(256) void march_kernel(
    const float* __restrict__ colors, const float* __restrict__ dens,
    const float* __restrict__ depths, const float* __restrict__ grads,
    float* __restrict__ out, const unsigned* __restrict__ mm,
    size_t o_depth, size_t o_w, size_t o_grad)
{
  __shared__ float red[4][64][33];           // +1 pad: column reads are 2-way (free)
  const int lane = threadIdx.x & 63;
  const int wid  = threadIdx.x >> 6;
  const size_t ray = (size_t)blockIdx.x * 4 + wid;

  // ---- loads (all coalesced) ----
  const float d   = depths[ray * 64 + lane];
  const float den = dens  [ray * 64 + lane];
  const float* gp = grads + ray * 192 + (size_t)lane * 3;
  const float g0 = gp[0], g1 = gp[1], g2 = gp[2];

  const float4* cp = (const float4*)(colors + ray * 2048 + (size_t)lane * 32);
  float4 col[8];
#pragma unroll
  for (int k = 0; k < 8; ++k) col[k] = cp[k];

  // ---- midpoints / alpha (lane 63 values are benign and unused) ----
  const float dn    = __shfl_down(d, 1);
  const float denn  = __shfl_down(den, 1);
  const float delta = dn - d;
  const float dm    = 0.5f * (den + denn) - 1.0f;
  // softplus(x) = max(x,0) + log1p(exp(-|x|))  (matches jax.nn.softplus)
  const float sp    = fmaxf(dm, 0.0f) + log1pf(expf(-fabsf(dm)));
  const float dd    = sp * delta;
  const float alpha = 1.0f - expf(-dd);
  const float t     = (1.0f - alpha) + 1e-10f;   // always > 0

  // ---- exclusive cumprod of t across lanes (Hillis-Steele) ----
  float p = t;
#pragma unroll
  for (int off = 1; off < 64; off <<= 1) {
    float v = __shfl_up(p, off);
    if (lane >= off) p *= v;
  }
  float excl = __shfl_up(p, 1);
  if (lane == 0) excl = 1.0f;
  const float w = (lane < 63) ? alpha * excl : 0.0f;

  // weights output [ray][63]
  if (lane < 63) out[o_w + ray * 63 + lane] = w;

  // sum_s w[s]*(x[s]+x[s+1])/2 == sum_s coef[s]*x[s], coef[s]=(w[s]+w[s-1])/2
  float wprev = __shfl_up(w, 1);
  if (lane == 0) wprev = 0.0f;
  const float coef = 0.5f * (w + wprev);

  // ---- scalar reductions: w_total, depth numerator, 3 grad channels ----
  float r0 = w, r1 = coef * d, r2 = coef * g0, r3 = coef * g1, r4 = coef * g2;
#pragma unroll
  for (int off = 32; off; off >>= 1) {
    r0 += __shfl_xor(r0, off);
    r1 += __shfl_xor(r1, off);
    r2 += __shfl_xor(r2, off);
    r3 += __shfl_xor(r3, off);
    r4 += __shfl_xor(r4, off);
  }

  // ---- rgb reduction via padded LDS column sums ----
  float* buf = &red[wid][0][0];
#pragma unroll
  for (int k = 0; k < 8; ++k) {
    buf[lane * 33 + 4 * k + 0] = coef * col[k].x;
    buf[lane * 33 + 4 * k + 1] = coef * col[k].y;
    buf[lane * 33 + 4 * k + 2] = coef * col[k].z;
    buf[lane * 33 + 4 * k + 3] = coef * col[k].w;
  }
  __syncthreads();

  const int c = lane & 31, h = lane >> 5;
  float sum = 0.0f;
#pragma unroll
  for (int i = 0; i < 32; ++i)
    sum += buf[(h * 32 + i) * 33 + c];
  sum += __shfl_xor(sum, 32);

  if (lane < 32)
    out[ray * 32 + c] = sum * 2.0f - 1.0f;   // composite_rgb*2-1

  if (lane == 0) {
    const float wt = r0;
    float cd = r1 / wt;
    if (cd != cd) cd = INFINITY;             // NaN -> inf (then clip -> dmax)
    const float dmin = funkey(mm[0]);
    const float dmax = funkey(mm[1]);
    cd = fminf(fmaxf(cd, dmin), dmax);
    out[o_depth + ray] = cd;
    const float add = 1.0f - wt;
    float* og = out + o_grad + ray * 3;
    og[0] = r2 + add;
    og[1] = r3 + add;
    og[2] = r4 + add;
  }
}

extern "C" void kernel_launch(void* const* d_in, const int* in_sizes, int n_in,
                              void* d_out, int out_size, void* d_ws, size_t ws_size,
                              hipStream_t stream) {
  const float* colors = (const float*)d_in[0];
  const float* dens   = (const float*)d_in[1];
  const float* depths = (const float*)d_in[2];
  const float* grads  = (const float*)d_in[3];
  float* out = (float*)d_out;
  unsigned* ws = (unsigned*)d_ws;

  const int ndep  = in_sizes[2];        // B*R*S = nrays*64
  const int nrays = ndep / 64;          // 65536
  const int C     = in_sizes[0] / ndep; // 32

  const size_t o_depth = (size_t)nrays * C;               // after rgb
  const size_t o_w     = o_depth + (size_t)nrays;         // after depth
  const size_t o_grad  = o_w + (size_t)nrays * 63;        // after weights

  hipLaunchKernelGGL(init_minmax, dim3(1), dim3(64), 0, stream, ws);
  hipLaunchKernelGGL(minmax_kernel, dim3(512), dim3(256), 0, stream,
                     (const float4*)depths, ws, ndep / 4);
  hipLaunchKernelGGL(march_kernel, dim3(nrays / 4), dim3(256), 0, stream,
                     colors, dens, depths, grads, out, ws, o_depth, o_w, o_grad);
}

// Round 2
// 179.073 us; speedup vs baseline: 1.0551x; 1.0551x over previous
//
#include <hip/hip_runtime.h>
#include <math.h>

// ---- float <-> order-preserving uint key (for global min/max via atomics) ----
static __device__ __forceinline__ unsigned fkey(float f) {
  unsigned u = __float_as_uint(f);
  return (u & 0x80000000u) ? ~u : (u | 0x80000000u);
}
static __device__ __forceinline__ float funkey(unsigned u) {
  unsigned b = (u & 0x80000000u) ? (u & 0x7FFFFFFFu) : ~u;
  return __uint_as_float(b);
}

__global__ __launch_bounds__(64) void init_minmax(unsigned* ws) {
  if (threadIdx.x == 0) { ws[0] = 0xFFFFFFFFu; ws[1] = 0u; }
}

__global__ __launch_bounds__(256) void minmax_kernel(const float4* __restrict__ d,
                                                     unsigned* __restrict__ ws, int n4) {
  int idx = blockIdx.x * 256 + threadIdx.x;
  int stride = gridDim.x * 256;
  float lmin = INFINITY, lmax = -INFINITY;
  for (int i = idx; i < n4; i += stride) {
    float4 v = d[i];
    lmin = fminf(lmin, fminf(fminf(v.x, v.y), fminf(v.z, v.w)));
    lmax = fmaxf(lmax, fmaxf(fmaxf(v.x, v.y), fmaxf(v.z, v.w)));
  }
#pragma unroll
  for (int off = 32; off; off >>= 1) {
    lmin = fminf(lmin, __shfl_xor(lmin, off));
    lmax = fmaxf(lmax, __shfl_xor(lmax, off));
  }
  if ((threadIdx.x & 63) == 0) {
    atomicMin(&ws[0], fkey(lmin));
    atomicMax(&ws[1], fkey(lmax));
  }
}

// One wave (64 lanes) per ray; lane = sample index s in [0,64).
// S=64, C=32 hard-coded per problem shapes. No LDS.
__global__ __launch_bounds__(256) void march_kernel(
    const float* __restrict__ colors, const float* __restrict__ dens,
    const float* __restrict__ depths, const float* __restrict__ grads,
    float* __restrict__ out, const unsigned* __restrict__ mm,
    size_t o_depth, size_t o_w, size_t o_grad)
{
  const int lane = threadIdx.x & 63;
  const size_t ray = (size_t)blockIdx.x * 4 + (threadIdx.x >> 6);

  // ---- per-sample loads (coalesced dwords) ----
  const float d   = depths[ray * 64 + lane];
  const float den = dens  [ray * 64 + lane];
  const float* gp = grads + ray * 192 + (size_t)lane * 3;
  const float g0 = gp[0], g1 = gp[1], g2 = gp[2];

  // ---- transposed color loads: each instruction reads a contiguous 1 KB ----
  // element e = k*256 + lane*4 + j  ->  sample s = k*8 + (lane>>3),
  //                                     channel c = (lane&7)*4 + j
  const float4* cp = (const float4*)(colors + ray * 2048);
  float4 col[8];
#pragma unroll
  for (int k = 0; k < 8; ++k) col[k] = cp[(size_t)k * 64 + lane];

  // ---- midpoints / alpha (lane 63 values are benign and unused) ----
  const float dn    = __shfl_down(d, 1);
  const float denn  = __shfl_down(den, 1);
  const float delta = dn - d;
  const float dm    = 0.5f * (den + denn) - 1.0f;
  // softplus(x) = max(x,0) + log1p(exp(-|x|))  (matches jax.nn.softplus)
  const float sp    = fmaxf(dm, 0.0f) + log1pf(expf(-fabsf(dm)));
  const float dd    = sp * delta;
  const float alpha = 1.0f - expf(-dd);
  const float t     = (1.0f - alpha) + 1e-10f;   // always > 0

  // ---- exclusive cumprod of t across lanes (Hillis-Steele) ----
  float p = t;
#pragma unroll
  for (int off = 1; off < 64; off <<= 1) {
    float v = __shfl_up(p, off);
    if (lane >= off) p *= v;
  }
  float excl = __shfl_up(p, 1);
  if (lane == 0) excl = 1.0f;
  const float w = (lane < 63) ? alpha * excl : 0.0f;

  // weights output [ray][63]
  if (lane < 63) out[o_w + ray * 63 + lane] = w;

  // sum_s w[s]*(x[s]+x[s+1])/2 == sum_s coef[s]*x[s], coef[s]=(w[s]+w[s-1])/2
  float wprev = __shfl_up(w, 1);
  if (lane == 0) wprev = 0.0f;
  const float coef = 0.5f * (w + wprev);

  // ---- rgb: accumulate coef[s]*color in registers, butterfly-reduce ----
  float a0 = 0.f, a1 = 0.f, a2 = 0.f, a3 = 0.f;
  const int sbase = lane >> 3;
#pragma unroll
  for (int k = 0; k < 8; ++k) {
    const float cf = __shfl(coef, k * 8 + sbase);
    a0 = fmaf(cf, col[k].x, a0);
    a1 = fmaf(cf, col[k].y, a1);
    a2 = fmaf(cf, col[k].z, a2);
    a3 = fmaf(cf, col[k].w, a3);
  }
#pragma unroll
  for (int off = 8; off <= 32; off <<= 1) {
    a0 += __shfl_xor(a0, off);
    a1 += __shfl_xor(a1, off);
    a2 += __shfl_xor(a2, off);
    a3 += __shfl_xor(a3, off);
  }
  if (lane < 8) {
    float4 o;
    o.x = fmaf(a0, 2.0f, -1.0f);
    o.y = fmaf(a1, 2.0f, -1.0f);
    o.z = fmaf(a2, 2.0f, -1.0f);
    o.w = fmaf(a3, 2.0f, -1.0f);
    ((float4*)(out + ray * 32))[lane] = o;
  }

  // ---- scalar reductions: w_total, depth numerator, 3 grad channels ----
  float r0 = w, r1 = coef * d, r2 = coef * g0, r3 = coef * g1, r4 = coef * g2;
#pragma unroll
  for (int off = 32; off; off >>= 1) {
    r0 += __shfl_xor(r0, off);
    r1 += __shfl_xor(r1, off);
    r2 += __shfl_xor(r2, off);
    r3 += __shfl_xor(r3, off);
    r4 += __shfl_xor(r4, off);
  }

  if (lane == 0) {
    const float wt = r0;
    float cd = r1 / wt;
    if (cd != cd) cd = INFINITY;             // NaN -> inf (then clip -> dmax)
    const float dmin = funkey(mm[0]);
    const float dmax = funkey(mm[1]);
    cd = fminf(fmaxf(cd, dmin), dmax);
    out[o_depth + ray] = cd;
    const float add = 1.0f - wt;
    float* og = out + o_grad + ray * 3;
    og[0] = r2 + add;
    og[1] = r3 + add;
    og[2] = r4 + add;
  }
}

extern "C" void kernel_launch(void* const* d_in, const int* in_sizes, int n_in,
                              void* d_out, int out_size, void* d_ws, size_t ws_size,
                              hipStream_t stream) {
  const float* colors = (const float*)d_in[0];
  const float* dens   = (const float*)d_in[1];
  const float* depths = (const float*)d_in[2];
  const float* grads  = (const float*)d_in[3];
  float* out = (float*)d_out;
  unsigned* ws = (unsigned*)d_ws;

  const int ndep  = in_sizes[2];        // B*R*S = nrays*64
  const int nrays = ndep / 64;          // 65536
  const int C     = in_sizes[0] / ndep; // 32

  const size_t o_depth = (size_t)nrays * C;               // after rgb
  const size_t o_w     = o_depth + (size_t)nrays;         // after depth
  const size_t o_grad  = o_w + (size_t)nrays * 63;        // after weights

  hipLaunchKernelGGL(init_minmax, dim3(1), dim3(64), 0, stream, ws);
  hipLaunchKernelGGL(minmax_kernel, dim3(512), dim3(256), 0, stream,
                     (const float4*)depths, ws, ndep / 4);
  hipLaunchKernelGGL(march_kernel, dim3(nrays / 4), dim3(256), 0, stream,
                     colors, dens, depths, grads, out, ws, o_depth, o_w, o_grad);
}

// Round 3
// 177.993 us; speedup vs baseline: 1.0615x; 1.0061x over previous
//
#include <hip/hip_runtime.h>
#include <math.h>

// ---- float <-> order-preserving uint key (for global min/max via atomics) ----
static __device__ __forceinline__ unsigned fkey(float f) {
  unsigned u = __float_as_uint(f);
  return (u & 0x80000000u) ? ~u : (u | 0x80000000u);
}
static __device__ __forceinline__ float funkey(unsigned u) {
  unsigned b = (u & 0x80000000u) ? (u & 0x7FFFFFFFu) : ~u;
  return __uint_as_float(b);
}

__global__ __launch_bounds__(64) void init_minmax(unsigned* ws) {
  if (threadIdx.x == 0) { ws[0] = 0xFFFFFFFFu; ws[1] = 0u; }
}

__global__ __launch_bounds__(256) void minmax_kernel(const float4* __restrict__ d,
                                                     unsigned* __restrict__ ws, int n4) {
  int idx = blockIdx.x * 256 + threadIdx.x;
  int stride = gridDim.x * 256;
  float lmin = INFINITY, lmax = -INFINITY;
  for (int i = idx; i < n4; i += stride) {
    float4 v = d[i];
    lmin = fminf(lmin, fminf(fminf(v.x, v.y), fminf(v.z, v.w)));
    lmax = fmaxf(lmax, fmaxf(fmaxf(v.x, v.y), fmaxf(v.z, v.w)));
  }
#pragma unroll
  for (int off = 32; off; off >>= 1) {
    lmin = fminf(lmin, __shfl_xor(lmin, off));
    lmax = fmaxf(lmax, __shfl_xor(lmax, off));
  }
  if ((threadIdx.x & 63) == 0) {
    atomicMin(&ws[0], fkey(lmin));
    atomicMax(&ws[1], fkey(lmax));
  }
}

// ---- DPP cross-lane helpers (VALU, no DS-unit traffic) ----
template <int CTRL, int RM, int BM>
static __device__ __forceinline__ float updf(float oldv, float src) {
  return __int_as_float(__builtin_amdgcn_update_dpp(
      __float_as_int(oldv), __float_as_int(src), CTRL, RM, BM, false));
}

// inclusive multiply-scan over 64 lanes (gfx9 row_shr + row_bcast sequence)
static __device__ __forceinline__ float mul_scan64(float x) {
  x *= updf<0x111, 0xf, 0xf>(1.0f, x);  // row_shr:1
  x *= updf<0x112, 0xf, 0xf>(1.0f, x);  // row_shr:2
  x *= updf<0x114, 0xf, 0xe>(1.0f, x);  // row_shr:4
  x *= updf<0x118, 0xf, 0xc>(1.0f, x);  // row_shr:8
  x *= updf<0x142, 0xa, 0xf>(1.0f, x);  // row_bcast:15 -> rows 1,3
  x *= updf<0x143, 0xc, 0xf>(1.0f, x);  // row_bcast:31 -> rows 2,3
  return x;
}

// 64-lane sum via DPP add-scan; total lands in lane 63
static __device__ __forceinline__ float sum64_lane63(float x) {
  x += updf<0x111, 0xf, 0xf>(0.0f, x);
  x += updf<0x112, 0xf, 0xf>(0.0f, x);
  x += updf<0x114, 0xf, 0xe>(0.0f, x);
  x += updf<0x118, 0xf, 0xc>(0.0f, x);
  x += updf<0x142, 0xa, 0xf>(0.0f, x);
  x += updf<0x143, 0xc, 0xf>(0.0f, x);
  return x;
}
static __device__ __forceinline__ float readlane63(float x) {
  return __int_as_float(__builtin_amdgcn_readlane(__float_as_int(x), 63));
}

// One wave (64 lanes) per ray; lane = sample index s in [0,64).
// S=64, C=32 hard-coded per problem shapes. No LDS; cross-lane mostly DPP.
__global__ __launch_bounds__(256) void march_kernel(
    const float* __restrict__ colors, const float* __restrict__ dens,
    const float* __restrict__ depths, const float* __restrict__ grads,
    float* __restrict__ out, const unsigned* __restrict__ mm,
    size_t o_depth, size_t o_w, size_t o_grad)
{
  const int lane = threadIdx.x & 63;
  const size_t ray = (size_t)blockIdx.x * 4 + (threadIdx.x >> 6);

  // ---- per-sample loads (coalesced dwords) ----
  const float d   = depths[ray * 64 + lane];
  const float den = dens  [ray * 64 + lane];
  const float* gp = grads + ray * 192 + (size_t)lane * 3;
  const float g0 = gp[0], g1 = gp[1], g2 = gp[2];

  // ---- transposed color loads: each instruction reads a contiguous 1 KB ----
  // element e = k*256 + lane*4 + j  ->  sample s = k*8 + (lane>>3),
  //                                     channel c = (lane&7)*4 + j
  const float4* cp = (const float4*)(colors + ray * 2048);
  float4 col[8];
#pragma unroll
  for (int k = 0; k < 8; ++k) col[k] = cp[(size_t)k * 64 + lane];

  // ---- midpoints / alpha (lane 63 values are benign and unused) ----
  const float dn    = __shfl_down(d, 1);
  const float denn  = __shfl_down(den, 1);
  const float delta = dn - d;
  const float dm    = 0.5f * (den + denn) - 1.0f;
  // softplus(x) = max(x,0) + log1p(exp(-|x|))  (matches jax.nn.softplus)
  const float sp    = fmaxf(dm, 0.0f) + log1pf(expf(-fabsf(dm)));
  const float dd    = sp * delta;
  const float alpha = 1.0f - expf(-dd);
  const float t     = (1.0f - alpha) + 1e-10f;   // always > 0

  // ---- exclusive cumprod of t across lanes (DPP inclusive scan, shift by 1) ----
  const float p = mul_scan64(t);
  float excl = __shfl_up(p, 1);
  if (lane == 0) excl = 1.0f;
  const float w = (lane < 63) ? alpha * excl : 0.0f;

  // weights output [ray][63]
  if (lane < 63) out[o_w + ray * 63 + lane] = w;

  // sum_s w[s]*(x[s]+x[s+1])/2 == sum_s coef[s]*x[s], coef[s]=(w[s]+w[s-1])/2
  float wprev = __shfl_up(w, 1);
  if (lane == 0) wprev = 0.0f;
  const float coef = 0.5f * (w + wprev);

  // ---- rgb: accumulate coef[s]*color in registers ----
  float a0 = 0.f, a1 = 0.f, a2 = 0.f, a3 = 0.f;
  const int sbase = lane >> 3;
#pragma unroll
  for (int k = 0; k < 8; ++k) {
    const float cf = __shfl(coef, k * 8 + sbase);
    a0 = fmaf(cf, col[k].x, a0);
    a1 = fmaf(cf, col[k].y, a1);
    a2 = fmaf(cf, col[k].z, a2);
    a3 = fmaf(cf, col[k].w, a3);
  }
  // reduce over lanes with equal (lane&7): ^8 via DPP row_ror:8, then ^16, ^32
  a0 += updf<0x128, 0xf, 0xf>(0.0f, a0);
  a1 += updf<0x128, 0xf, 0xf>(0.0f, a1);
  a2 += updf<0x128, 0xf, 0xf>(0.0f, a2);
  a3 += updf<0x128, 0xf, 0xf>(0.0f, a3);
#pragma unroll
  for (int off = 16; off <= 32; off <<= 1) {
    a0 += __shfl_xor(a0, off);
    a1 += __shfl_xor(a1, off);
    a2 += __shfl_xor(a2, off);
    a3 += __shfl_xor(a3, off);
  }
  if (lane < 8) {
    float4 o;
    o.x = fmaf(a0, 2.0f, -1.0f);
    o.y = fmaf(a1, 2.0f, -1.0f);
    o.z = fmaf(a2, 2.0f, -1.0f);
    o.w = fmaf(a3, 2.0f, -1.0f);
    ((float4*)(out + ray * 32))[lane] = o;
  }

  // ---- scalar reductions via DPP add-scan + readlane (uniform results) ----
  const float wt = readlane63(sum64_lane63(w));
  const float s1 = readlane63(sum64_lane63(coef * d));
  const float s2 = readlane63(sum64_lane63(coef * g0));
  const float s3 = readlane63(sum64_lane63(coef * g1));
  const float s4 = readlane63(sum64_lane63(coef * g2));

  if (lane == 0) {
    float cd = s1 / wt;
    if (cd != cd) cd = INFINITY;             // NaN -> inf (then clip -> dmax)
    const float dmin = funkey(mm[0]);
    const float dmax = funkey(mm[1]);
    cd = fminf(fmaxf(cd, dmin), dmax);
    out[o_depth + ray] = cd;
    const float add = 1.0f - wt;
    float* og = out + o_grad + ray * 3;
    og[0] = s2 + add;
    og[1] = s3 + add;
    og[2] = s4 + add;
  }
}

extern "C" void kernel_launch(void* const* d_in, const int* in_sizes, int n_in,
                              void* d_out, int out_size, void* d_ws, size_t ws_size,
                              hipStream_t stream) {
  const float* colors = (const float*)d_in[0];
  const float* dens   = (const float*)d_in[1];
  const float* depths = (const float*)d_in[2];
  const float* grads  = (const float*)d_in[3];
  float* out = (float*)d_out;
  unsigned* ws = (unsigned*)d_ws;

  const int ndep  = in_sizes[2];        // B*R*S = nrays*64
  const int nrays = ndep / 64;          // 65536
  const int C     = in_sizes[0] / ndep; // 32

  const size_t o_depth = (size_t)nrays * C;               // after rgb
  const size_t o_w     = o_depth + (size_t)nrays;         // after depth
  const size_t o_grad  = o_w + (size_t)nrays * 63;        // after weights

  hipLaunchKernelGGL(init_minmax, dim3(1), dim3(64), 0, stream, ws);
  hipLaunchKernelGGL(minmax_kernel, dim3(512), dim3(256), 0, stream,
                     (const float4*)depths, ws, ndep / 4);
  hipLaunchKernelGGL(march_kernel, dim3(nrays / 4), dim3(256), 0, stream,
                     colors, dens, depths, grads, out, ws, o_depth, o_w, o_grad);
}